// Round 1
// 335.462 us; speedup vs baseline: 1.0099x; 1.0099x over previous
//
#include <hip/hip_runtime.h>
#include <math.h>
#include <float.h>

// Problem constants (from reference): B=32, S=2048, D=1024, fp32 in/out.
#define BD 32
#define SD 2048
#define DD 1024
#define NTHREADS 256
#define NW 4   // waves per block

// Kernel 1: per (batch, S-chunk) partial online-softmax attention.
// Each WAVE owns whole rows (lane i holds d = lane*4 + 256*j, j=0..3).
// v2 changes vs previous session's kernel:
//  - C is a compile-time template param -> rpw is constexpr -> loops unroll.
//  - masked-row skip is now BRANCH-FREE: a ballot builds the valid-row
//    bitmask once; the loop walks only set bits (no per-row branch that
//    blocks load hoisting).
//  - TWO valid rows are processed per iteration: 8 KB of loads in flight
//    per wave, two independent shuffle-reduce chains interleave, and one
//    shared online-softmax rescale (single alpha pass) serves both rows.
template<int C>
__global__ __launch_bounds__(NTHREADS, 4) void attn_partial(
    const float* __restrict__ target,   // [B,D]
    const float* __restrict__ context,  // [B,S,D]
    const float* __restrict__ mask,     // [B,S]
    float* __restrict__ wsO,            // [B*C, D]
    float* __restrict__ wsM,            // [B*C]
    float* __restrict__ wsL)            // [B*C]
{
    constexpr int rows = SD / C;        // rows per block (32 at C=64)
    constexpr int rpw  = rows / NW;     // rows per wave  (8  at C=64)
    static_assert(rows % NW == 0 && rpw <= 64, "bad chunking");

    const int g = blockIdx.x;
    const int b = g / C;
    const int c = g % C;
    const int s0 = c * rows;
    const int t = threadIdx.x;
    const int lane = t & 63;
    const int w = t >> 6;

    // query fragment: lane owns d = lane*4 + 256*j
    float4 tgt[4];
    #pragma unroll
    for (int j = 0; j < 4; ++j)
        tgt[j] = *(const float4*)(target + (size_t)b * DD + j * 256 + lane * 4);

    const int r0 = w * rpw;
    const float* ctx = context + ((size_t)b * SD + s0 + r0) * DD + lane * 4;
    const float* mk  = mask + (size_t)b * SD + s0 + r0;

    // one coalesced load of this wave's mask values; compact to a bitmask.
    // Valid rows have weight exp(s - m); masked rows would contribute
    // exp(-1e8 - m) == 0.0f exactly in fp32, so skipping them is exact
    // AND skips their 4 KB context-row load (halves HBM traffic).
    float mlane = (lane < rpw) ? mk[lane] : 0.f;
    unsigned long long rem = __ballot((lane < rpw) && (mlane != 0.f));

    float4 o[4];
    #pragma unroll
    for (int j = 0; j < 4; ++j) o[j] = make_float4(0.f, 0.f, 0.f, 0.f);
    // -FLT_MAX (not -INF) sentinel: empty waves/chunks produce clean zeros
    // (exp(-FLT_MAX - x) == 0, exp(-FLT_MAX + FLT_MAX) == 1) -- no NaN paths.
    float m = -FLT_MAX, l = 0.f;

    while (rem) {
        const int i0 = (int)__builtin_ctzll(rem); rem &= rem - 1;
        int i1 = -1;
        if (rem) { i1 = (int)__builtin_ctzll(rem); rem &= rem - 1; }
        const float* rp0 = ctx + (size_t)i0 * DD;
        const float* rp1 = ctx + (size_t)(i1 >= 0 ? i1 : i0) * DD; // dup = L1 hit
        float4 x0[4], x1[4];
        #pragma unroll
        for (int j = 0; j < 4; ++j) x0[j] = *(const float4*)(rp0 + j * 256);
        #pragma unroll
        for (int j = 0; j < 4; ++j) x1[j] = *(const float4*)(rp1 + j * 256);

        float sa = 0.f, sb = 0.f;
        #pragma unroll
        for (int j = 0; j < 4; ++j) {
            sa = fmaf(x0[j].x, tgt[j].x, sa);
            sa = fmaf(x0[j].y, tgt[j].y, sa);
            sa = fmaf(x0[j].z, tgt[j].z, sa);
            sa = fmaf(x0[j].w, tgt[j].w, sa);
            sb = fmaf(x1[j].x, tgt[j].x, sb);
            sb = fmaf(x1[j].y, tgt[j].y, sb);
            sb = fmaf(x1[j].z, tgt[j].z, sb);
            sb = fmaf(x1[j].w, tgt[j].w, sb);
        }
        // two independent butterfly chains -> they interleave in the pipe
        #pragma unroll
        for (int off = 32; off > 0; off >>= 1) {
            sa += __shfl_xor(sa, off);
            sb += __shfl_xor(sb, off);
        }
        if (i1 < 0) sb = -FLT_MAX;      // second slot empty -> weight 0

        const float mnew  = fmaxf(m, fmaxf(sa, sb));   // v_max3 candidate
        const float alpha = __expf(m - mnew);          // 0 on first pair
        const float p0 = __expf(sa - mnew);
        const float p1 = (i1 >= 0) ? __expf(sb - mnew) : 0.f;
        l = fmaf(l, alpha, p0 + p1);
        #pragma unroll
        for (int j = 0; j < 4; ++j) {
            o[j].x = fmaf(p1, x1[j].x, fmaf(p0, x0[j].x, o[j].x * alpha));
            o[j].y = fmaf(p1, x1[j].y, fmaf(p0, x0[j].y, o[j].y * alpha));
            o[j].z = fmaf(p1, x1[j].z, fmaf(p0, x0[j].z, o[j].z * alpha));
            o[j].w = fmaf(p1, x1[j].w, fmaf(p0, x0[j].w, o[j].w * alpha));
        }
        m = mnew;
    }

    // ---- block-level merge of the 4 per-wave partials (2 barriers total) ----
    __shared__ float sM[NW];
    __shared__ float sL[NW];
    __shared__ float sO[NW][DD];        // 16 KB
    if (lane == 0) { sM[w] = m; sL[w] = l; }
    __syncthreads();
    const float M = fmaxf(fmaxf(sM[0], sM[1]), fmaxf(sM[2], sM[3]));
    float lsum = 0.f;
    #pragma unroll
    for (int ww = 0; ww < NW; ++ww) lsum += sL[ww] * __expf(sM[ww] - M);
    const float aw = __expf(m - M);     // m wave-uniform; 1 if both -FLT_MAX
    #pragma unroll
    for (int j = 0; j < 4; ++j) {
        float4 v = make_float4(o[j].x * aw, o[j].y * aw, o[j].z * aw, o[j].w * aw);
        *(float4*)(&sO[w][j * 256 + lane * 4]) = v;
    }
    __syncthreads();
    float4 acc = make_float4(0.f, 0.f, 0.f, 0.f);
    #pragma unroll
    for (int ww = 0; ww < NW; ++ww) {
        float4 v = *(const float4*)(&sO[ww][t * 4]);
        acc.x += v.x; acc.y += v.y; acc.z += v.z; acc.w += v.w;
    }
    *(float4*)(wsO + (size_t)g * DD + t * 4) = acc;
    if (t == 0) { wsM[g] = M; wsL[g] = lsum; }
}

// Kernel 2: combine C partials per batch with global max rescaling.
// v2: grid = B*8 blocks x 128 threads (2x parallelism), constexpr-C chunk
// loop fully unrolled with 4 independent accumulators -> all loads in
// flight instead of a serial dependent-FMA chain over cold 4KB-strided reads.
template<int C>
__global__ __launch_bounds__(128) void attn_combine(
    const float* __restrict__ wsO,
    const float* __restrict__ wsM,
    const float* __restrict__ wsL,
    float* __restrict__ out)
{
    static_assert(C >= 4 && (C % 4) == 0 && C <= 64, "bad C");
    const int bb = blockIdx.x;          // B*8
    const int b = bb >> 3;
    const int d0 = (bb & 7) * 128;
    const int t = threadIdx.x;          // 0..127
    __shared__ float wgt[64];           // per-chunk normalized weights

    if (t < 64) {
        float mv = (t < C) ? wsM[b * C + t] : -FLT_MAX;
        float mred = mv;
        #pragma unroll
        for (int off = 32; off > 0; off >>= 1)
            mred = fmaxf(mred, __shfl_xor(mred, off));
        float lw = (t < C) ? wsL[b * C + t] * __expf(mv - mred) : 0.f;
        float lsum = lw;
        #pragma unroll
        for (int off = 32; off > 0; off >>= 1)
            lsum += __shfl_xor(lsum, off);
        wgt[t] = (t < C) ? __expf(mv - mred) / lsum : 0.f;
    }
    __syncthreads();

    const float* po = wsO + (size_t)b * C * DD + d0 + t;
    float a0 = 0.f, a1 = 0.f, a2 = 0.f, a3 = 0.f;
    #pragma unroll
    for (int c = 0; c < C; c += 4) {
        a0 = fmaf(wgt[c + 0], po[(size_t)(c + 0) * DD], a0);
        a1 = fmaf(wgt[c + 1], po[(size_t)(c + 1) * DD], a1);
        a2 = fmaf(wgt[c + 2], po[(size_t)(c + 2) * DD], a2);
        a3 = fmaf(wgt[c + 3], po[(size_t)(c + 3) * DD], a3);
    }
    out[(size_t)b * DD + d0 + t] = (a0 + a1) + (a2 + a3);
}

extern "C" void kernel_launch(void* const* d_in, const int* in_sizes, int n_in,
                              void* d_out, int out_size, void* d_ws, size_t ws_size,
                              hipStream_t stream) {
    const float* target  = (const float*)d_in[0];  // [B,D]
    const float* context = (const float*)d_in[1];  // [B,S,D]
    const float* mask    = (const float*)d_in[2];  // [B,S]
    float* out = (float*)d_out;                    // [B,D]

    const size_t need64 = (size_t)BD * 64 * (DD + 2) * sizeof(float);
    if (ws_size >= need64) {
        constexpr int C = 64;                      // 2048 blocks (~8/CU)
        float* wsO = (float*)d_ws;                 // [B*C, D]
        float* wsM = wsO + (size_t)BD * C * DD;    // [B*C]
        float* wsL = wsM + (size_t)BD * C;         // [B*C]
        attn_partial<C><<<BD * C, NTHREADS, 0, stream>>>(target, context, mask, wsO, wsM, wsL);
        attn_combine<C><<<BD * 8, 128, 0, stream>>>(wsO, wsM, wsL, out);
    } else {
        constexpr int C = 8;                       // 1.05 MB workspace fallback
        float* wsO = (float*)d_ws;
        float* wsM = wsO + (size_t)BD * C * DD;
        float* wsL = wsM + (size_t)BD * C;
        attn_partial<C><<<BD * C, NTHREADS, 0, stream>>>(target, context, mask, wsO, wsM, wsL);
        attn_combine<C><<<BD * 8, 128, 0, stream>>>(wsO, wsM, wsL, out);
    }
}